// Round 6
// baseline (150.650 us; speedup 1.0000x reference)
//
#include <hip/hip_runtime.h>
#include <hip/hip_bf16.h>
#include <cstdint>

// Problem constants: T=512 timesteps/slots, B=64 batch, E=512 embed.
#define TT 512
#define BB 64
#define EE 512

typedef short bf16x8 __attribute__((ext_vector_type(8)));   // 8 bf16 = 4 VGPRs
typedef float f32x4  __attribute__((ext_vector_type(4)));   // MFMA C/D frag

// RNE pack of (a -> low16, b -> high16); compiler emits v_cvt_pk_bf16_f32.
static __device__ __forceinline__ unsigned bpack(float a, float b) {
    union { __hip_bfloat162 h; unsigned u; } cv;
    cv.h = __float22bfloat162_rn(make_float2(a, b));
    return cv.u;
}

// Barrier that does NOT drain vmcnt: LDS traffic is made visible
// (lgkmcnt(0)), in-flight global register prefetches stay outstanding.
static __device__ __forceinline__ void barrier_lds_only() {
    asm volatile("s_waitcnt lgkmcnt(0)" ::: "memory");
    __builtin_amdgcn_s_barrier();
}

// ---------------------------------------------------------------------------
// R5 structure (balanced 128-row tile pairs, double-buffered single-barrier
// pipeline) with 64-col n-slices for 4x block concurrency.
//   R5 post-mortem: grid 512 -> 2 blocks/CU -> 2 waves/SIMD -> Occupancy 14%,
//   ~2.8K cycles per ~700-cycle barrier interval (latency-bound, no pipe
//   above 34%). This version: grid 1024 (64b x 8n x 2pairs), LDS 34.8 KB ->
//   4 blocks/CU, 4 waves/SIMD. Same per-CU work, same V traffic, 2x latency
//   cover.
//
//   wave-0 prologue: queue scan (closed form, max-plus wave scan) -> Rs/CUs.
//     Q(t) = relu(Q(t-1) - u_t) + d_t,  CU(t) = sum u,  R(t) = Q(t) + CU(t)
//   main: out[t,b,e] = sum_i C[t,i] * V[i,b,e],
//     C[t,i] = min(relu(R_i-CU_t),1) - min(relu(R_{i-1}-CU_t),1)  (0 for i>t)
//
// m in FOUR 128-row tiles; tile MI needs 4(MI+1) BK=32 chunks; pairs
// {MI0,MI3} / {MI1,MI2} both = 20 chunks -> zero tail. Small tile first.
// Per chunk: ONE lgkmcnt+s_barrier; vmcnt never drained (1-chunk-ahead
// register prefetch). 4 waves (2m x 2n), 64m x 32n per wave, acc[4][2]
// (32 VGPR; R4's acc[8][4] spilled -> 10x traffic, never again).
// Grid: 1024 blocks x 256 threads; id bits [2:0]=b%8(xcd), [5:3]=b-hi,
// [8:6]=n-slice, [9]=pair. Co-resident 4 blocks on a CU share batch b.
// ---------------------------------------------------------------------------
__global__ __launch_bounds__(256, 4) void gemm_fused_kernel(
        const float* __restrict__ V,    // [T(i)][B][E]
        const float* __restrict__ U,    // [T][B]
        const float* __restrict__ D,    // [T][B]
        float* __restrict__ out) {      // [T(t)][B][E]
    const int id   = blockIdx.x;
    const int b    = (id & 7) + 8 * ((id >> 3) & 7);
    const int n0   = ((id >> 6) & 7) * 64;
    const int pr   = id >> 9;             // pair 0: {0,3}, pair 1: {1,2}
    const int MIa  = pr;                  // small tile first
    const int MIb  = 3 - pr;
    const int Ka   = 4 * (MIa + 1);       // 4 or 8
    const int NIT  = 20;                  // identical for both pairs

    __shared__ __align__(16) unsigned short As[2][128 * 40];  // [t][i] stride 40
    __shared__ __align__(16) unsigned short Bs[2][64 * 40];   // [e][i] stride 40
    __shared__ __align__(16) float Rs[TT];
    __shared__ __align__(16) float CUs[TT];

    const int tid  = threadIdx.x;
    const int wave = tid >> 6;
    const int lane = tid & 63;

    // A-fill: thread owns row a_t, 16 contiguous i.
    const int a_t  = tid >> 1;            // 0..127
    const int a_i0 = (tid & 1) * 16;      // 0 or 16
    // B-fill: thread owns 4k x 2e micro-tile (64e x 32k / 256 threads).
    const int b_e2 = (lane & 31) * 2;             // 0..62
    const int b_k4 = (wave * 2 + (lane >> 5)) * 4; // 0,4,...,28
    // Fragments: 2x2 waves, 64m x 32n per wave.
    const int wm   = (wave >> 1) * 64;
    const int wn   = (wave & 1) * 32;
    const int frow = lane & 15;
    const int quad = lane >> 4;

    const float* Vb = V + (size_t)b * EE + n0 + b_e2;   // + k*(BB*EE)

    // Prefetch chunk 0 (k rows b_k4..b_k4+3); latency hides under the scan.
    float2 v[4];
    #pragma unroll
    for (int r = 0; r < 4; ++r)
        v[r] = *(const float2*)(Vb + (size_t)(b_k4 + r) * (BB * EE));

    // ---- In-block scan (wave 0 only): R/CU for batch b into LDS ----
    if (wave == 0) {
        float u[8], d[8];
        #pragma unroll
        for (int j = 0; j < 8; ++j) {
            u[j] = U[(lane * 8 + j) * BB + b];
            d[j] = D[(lane * 8 + j) * BB + b];
        }
        float A = 0.f, Bv = -1e30f, S = 0.f;
        #pragma unroll
        for (int j = 0; j < 8; ++j) {
            const float a = d[j] - u[j];
            Bv = fmaxf(Bv + a, d[j]);
            A += a;
            S += u[j];
        }
        #pragma unroll
        for (int off = 1; off < 64; off <<= 1) {
            const float Ap = __shfl_up(A, off);
            const float Bp = __shfl_up(Bv, off);
            const float Sp = __shfl_up(S, off);
            if (lane >= off) {
                Bv = fmaxf(Bp + A, Bv);
                A  = A + Ap;
                S  = S + Sp;
            }
        }
        float Aex = __shfl_up(A, 1), Bex = __shfl_up(Bv, 1), Sex = __shfl_up(S, 1);
        if (lane == 0) { Aex = 0.f; Bex = -1e30f; Sex = 0.f; }
        float Q  = fmaxf(Aex, Bex);
        float cu = Sex;
        float rv[8], cv[8];
        #pragma unroll
        for (int j = 0; j < 8; ++j) {
            cu += u[j];
            Q = fmaxf(Q - u[j], 0.f) + d[j];
            rv[j] = Q + cu;
            cv[j] = cu;
        }
        *(float4*)(Rs  + lane * 8)     = make_float4(rv[0], rv[1], rv[2], rv[3]);
        *(float4*)(Rs  + lane * 8 + 4) = make_float4(rv[4], rv[5], rv[6], rv[7]);
        *(float4*)(CUs + lane * 8)     = make_float4(cv[0], cv[1], cv[2], cv[3]);
        *(float4*)(CUs + lane * 8 + 4) = make_float4(cv[4], cv[5], cv[6], cv[7]);
    }
    barrier_lds_only();                   // publishes Rs/CUs; v stays in flight

    const float cuA = CUs[MIa * 128 + a_t];
    const float cuB = CUs[MIb * 128 + a_t];

    // Stage A (closed form) + B (pack prefetched V) for iteration it_t.
    auto fill = [&](int it_t, int buf) {
        const bool inB = (it_t >= Ka);
        const int  MI  = inB ? MIb : MIa;
        const int  kk  = inB ? (it_t - Ka) : it_t;
        const float cu_t = inB ? cuB : cuA;
        const int  m0  = MI * 128;
        const int  k0  = kk * 32;
        // ---- A: 16 coeffs per thread ----
        {
            const int i = k0 + a_i0;
            const float4 r0 = *(const float4*)(Rs + i);
            const float4 r1 = *(const float4*)(Rs + i + 4);
            const float4 r2 = *(const float4*)(Rs + i + 8);
            const float4 r3 = *(const float4*)(Rs + i + 12);
            const float rv[16] = {r0.x, r0.y, r0.z, r0.w, r1.x, r1.y, r1.z, r1.w,
                                  r2.x, r2.y, r2.z, r2.w, r3.x, r3.y, r3.z, r3.w};
            const float prev = (i == 0) ? 0.f : Rs[i - 1];
            float pvp = fminf(fmaxf(prev - cu_t, 0.f), 1.f);
            float c[16];
            if (k0 < m0) {                    // strictly below diagonal
                #pragma unroll
                for (int j = 0; j < 16; ++j) {
                    const float pv = fminf(fmaxf(rv[j] - cu_t, 0.f), 1.f);
                    c[j] = pv - pvp;
                    pvp = pv;
                }
            } else {                          // diagonal chunk: zero for i > t
                const int t = m0 + a_t;
                #pragma unroll
                for (int j = 0; j < 16; ++j) {
                    const float pv = fminf(fmaxf(rv[j] - cu_t, 0.f), 1.f);
                    c[j] = (i + j <= t) ? (pv - pvp) : 0.f;
                    pvp = pv;
                }
            }
            uint4 w0, w1;
            w0.x = bpack(c[0], c[1]);   w0.y = bpack(c[2], c[3]);
            w0.z = bpack(c[4], c[5]);   w0.w = bpack(c[6], c[7]);
            w1.x = bpack(c[8], c[9]);   w1.y = bpack(c[10], c[11]);
            w1.z = bpack(c[12], c[13]); w1.w = bpack(c[14], c[15]);
            *(uint4*)(As[buf] + a_t * 40 + a_i0)     = w0;
            *(uint4*)(As[buf] + a_t * 40 + a_i0 + 8) = w1;
        }
        // ---- B: pack prefetched 4k x 2e of V, register transpose ----
        {
            uint2 q0, q1;
            q0.x = bpack(v[0].x, v[1].x); q0.y = bpack(v[2].x, v[3].x);
            q1.x = bpack(v[0].y, v[1].y); q1.y = bpack(v[2].y, v[3].y);
            *(uint2*)(Bs[buf] + b_e2 * 40 + b_k4)       = q0;
            *(uint2*)(Bs[buf] + (b_e2 + 1) * 40 + b_k4) = q1;
        }
    };

    // Issue global V loads for iteration it_t (consumed by fill(it_t)).
    auto prefetch = [&](int it_t) {
        const int kk = (it_t >= Ka) ? (it_t - Ka) : it_t;
        const float* vp = Vb + (size_t)(kk * 32 + b_k4) * (BB * EE);
        #pragma unroll
        for (int r = 0; r < 4; ++r)
            v[r] = *(const float2*)(vp + (size_t)r * (BB * EE));
    };

    f32x4 acc[4][2];
    #pragma unroll
    for (int mi = 0; mi < 4; ++mi)
        #pragma unroll
        for (int ni = 0; ni < 2; ++ni)
            acc[mi][ni] = f32x4{0.f, 0.f, 0.f, 0.f};

    // Epilogue: C/D layout col=lane&15, row=quad*4+r (m89/m91 verified).
    auto epilogue = [&](int m0t) {
        #pragma unroll
        for (int mi = 0; mi < 4; ++mi) {
            #pragma unroll
            for (int r = 0; r < 4; ++r) {
                const int t = m0t + wm + mi * 16 + quad * 4 + r;
                float* orow = out + ((size_t)t * BB + b) * EE + n0 + wn + frow;
                #pragma unroll
                for (int ni = 0; ni < 2; ++ni)
                    orow[ni * 16] = acc[mi][ni][r];
            }
        }
    };

    // Prologue: stage iteration 0 into buf 0, prefetch iteration 1.
    fill(0, 0);
    prefetch(1);
    barrier_lds_only();

    for (int it = 0; it < NIT; ++it) {
        const int cur = it & 1;

        bf16x8 af[4], bf[2];
        #pragma unroll
        for (int mi = 0; mi < 4; ++mi)
            af[mi] = *(const bf16x8*)(As[cur] + (wm + mi * 16 + frow) * 40 + quad * 8);
        #pragma unroll
        for (int ni = 0; ni < 2; ++ni)
            bf[ni] = *(const bf16x8*)(Bs[cur] + (wn + ni * 16 + frow) * 40 + quad * 8);

        if (it + 1 < NIT) {
            fill(it + 1, cur ^ 1);        // writes go to the OTHER buffer
            if (it + 2 < NIT) prefetch(it + 2);
        }

        barrier_lds_only();               // drains LDS only; vmcnt in flight

        #pragma unroll
        for (int mi = 0; mi < 4; ++mi)
            #pragma unroll
            for (int ni = 0; ni < 2; ++ni)
                acc[mi][ni] = __builtin_amdgcn_mfma_f32_16x16x32_bf16(
                    af[mi], bf[ni], acc[mi][ni], 0, 0, 0);

        if (it == Ka - 1) {               // small tile complete: flush + reset
            epilogue(MIa * 128);
            #pragma unroll
            for (int mi = 0; mi < 4; ++mi)
                #pragma unroll
                for (int ni = 0; ni < 2; ++ni)
                    acc[mi][ni] = f32x4{0.f, 0.f, 0.f, 0.f};
        }
    }
    epilogue(MIb * 128);
}

extern "C" void kernel_launch(void* const* d_in, const int* in_sizes, int n_in,
                              void* d_out, int out_size, void* d_ws, size_t ws_size,
                              hipStream_t stream) {
    const float* V = (const float*)d_in[0];   // [T,B,E]
    const float* U = (const float*)d_in[1];   // [T,B]
    const float* D = (const float*)d_in[2];   // [T,B]
    float* out = (float*)d_out;               // [T,B,E]

    gemm_fused_kernel<<<dim3(1024), dim3(256), 0, stream>>>(V, U, D, out);
}

// Round 7
// 135.320 us; speedup vs baseline: 1.1133x; 1.1133x over previous
//
#include <hip/hip_runtime.h>
#include <hip/hip_bf16.h>
#include <cstdint>

// Problem constants: T=512 timesteps/slots, B=64 batch, E=512 embed.
#define TT 512
#define BB 64
#define EE 512

typedef short bf16x8 __attribute__((ext_vector_type(8)));   // 8 bf16 = 4 VGPRs
typedef float f32x4  __attribute__((ext_vector_type(4)));   // MFMA C/D frag

// RNE pack of (a -> low16, b -> high16); compiler emits v_cvt_pk_bf16_f32.
static __device__ __forceinline__ unsigned bpack(float a, float b) {
    union { __hip_bfloat162 h; unsigned u; } cv;
    cv.h = __float22bfloat162_rn(make_float2(a, b));
    return cv.u;
}

// Barrier that does NOT drain vmcnt: LDS traffic is made visible
// (lgkmcnt(0)), in-flight global register prefetches stay outstanding.
static __device__ __forceinline__ void barrier_lds_only() {
    asm volatile("s_waitcnt lgkmcnt(0)" ::: "memory");
    __builtin_amdgcn_s_barrier();
}

// ---------------------------------------------------------------------------
// R5 structure (best measured: 47 us; balanced 128-row tile pairs, exact-
// compulsory WRITE, no spill) with 512-THREAD blocks for 2x wave concurrency.
//   R5 defect: grid 512 -> 2 blocks/CU x 4 waves = 2 waves/SIMD; interval
//   ~2.8K cycles vs ~700 cycles issue work -> CU idles in lgkm/barrier/vmcnt.
//   R6 fixed occupancy by shrinking tiles and paid +25.6 MB in BOTH fetch and
//   write (scratch) + 2x conflicts -> 64 us. Here: SAME tiles, SAME traffic,
//   8 waves/block -> 4 waves/SIMD (two 8-wave blocks per CU interleave).
//
//   wave-0 prologue: queue scan (closed form, max-plus wave scan) -> Rs/CUs.
//     Q(t) = relu(Q(t-1) - u_t) + d_t,  CU(t) = sum u,  R(t) = Q(t) + CU(t)
//   main: out[t,b,e] = sum_i C[t,i] * V[i,b,e],
//     C[t,i] = min(relu(R_i-CU_t),1) - min(relu(R_{i-1}-CU_t),1)  (0 for i>t)
//
// m in FOUR 128-row tiles (prefix amplification 2.5x; 64-row splits measured
// worse). Tile MI needs 4(MI+1) BK=32 chunks; pairs {MI0,MI3} / {MI1,MI2}
// both = 20 chunks -> zero tail. Small tile first. Per chunk: ONE
// lgkmcnt+s_barrier; vmcnt never drained (1-chunk-ahead register prefetch).
// 8 waves (2m x 4n), 64m x 32n per wave, acc[4][2] (32 VGPR). A-fill is 8
// coeffs/thread (serial pvp chain halved vs R5's 16).
// Grid: 512 blocks x 512 threads; id bits [2:0]=b%8(xcd), [5:3]=b-hi,
// [7:6]=n-tile(128col), [8]=pair. LDS 45 KB -> 2 blocks/CU, 16 waves/CU.
// ---------------------------------------------------------------------------
__global__ __launch_bounds__(512, 2) void gemm_fused_kernel(
        const float* __restrict__ V,    // [T(i)][B][E]
        const float* __restrict__ U,    // [T][B]
        const float* __restrict__ D,    // [T][B]
        float* __restrict__ out) {      // [T(t)][B][E]
    const int id   = blockIdx.x;
    const int b    = (id & 7) + 8 * ((id >> 3) & 7);
    const int n0   = ((id >> 6) & 3) * 128;
    const int pr   = id >> 8;             // pair 0: {0,3}, pair 1: {1,2}
    const int MIa  = pr;                  // small tile first
    const int MIb  = 3 - pr;
    const int Ka   = 4 * (MIa + 1);       // 4 or 8
    const int NIT  = 20;                  // identical for both pairs

    __shared__ __align__(16) unsigned short As[2][128 * 40];  // [t][i] stride 40
    __shared__ __align__(16) unsigned short Bs[2][128 * 40];  // [e][i] stride 40
    __shared__ __align__(16) float Rs[TT];
    __shared__ __align__(16) float CUs[TT];

    const int tid  = threadIdx.x;
    const int wave = tid >> 6;            // 0..7
    const int lane = tid & 63;

    // A-fill: thread owns row a_t, 8 contiguous i (512 threads cover 128x32).
    const int a_t  = tid >> 2;            // 0..127
    const int a_i0 = (tid & 3) * 8;       // 0,8,16,24
    // B-fill: thread owns 4k x 2e micro-tile (128e x 32k / 512 threads).
    const int b_e2 = lane * 2;            // 0..126
    const int b_k4 = wave * 4;            // 0..28
    // Fragments: 2m x 4n waves, 64m x 32n per wave.
    const int wm   = (wave >> 2) * 64;
    const int wn   = (wave & 3) * 32;
    const int frow = lane & 15;
    const int quad = lane >> 4;

    const float* Vb = V + (size_t)b * EE + n0 + b_e2;   // + k*(BB*EE)

    // Prefetch chunk 0 (k rows b_k4..b_k4+3); latency hides under the scan.
    float2 v[4];
    #pragma unroll
    for (int r = 0; r < 4; ++r)
        v[r] = *(const float2*)(Vb + (size_t)(b_k4 + r) * (BB * EE));

    // ---- In-block scan (wave 0 only): R/CU for batch b into LDS ----
    if (wave == 0) {
        float u[8], d[8];
        #pragma unroll
        for (int j = 0; j < 8; ++j) {
            u[j] = U[(lane * 8 + j) * BB + b];
            d[j] = D[(lane * 8 + j) * BB + b];
        }
        float A = 0.f, Bv = -1e30f, S = 0.f;
        #pragma unroll
        for (int j = 0; j < 8; ++j) {
            const float a = d[j] - u[j];
            Bv = fmaxf(Bv + a, d[j]);
            A += a;
            S += u[j];
        }
        #pragma unroll
        for (int off = 1; off < 64; off <<= 1) {
            const float Ap = __shfl_up(A, off);
            const float Bp = __shfl_up(Bv, off);
            const float Sp = __shfl_up(S, off);
            if (lane >= off) {
                Bv = fmaxf(Bp + A, Bv);
                A  = A + Ap;
                S  = S + Sp;
            }
        }
        float Aex = __shfl_up(A, 1), Bex = __shfl_up(Bv, 1), Sex = __shfl_up(S, 1);
        if (lane == 0) { Aex = 0.f; Bex = -1e30f; Sex = 0.f; }
        float Q  = fmaxf(Aex, Bex);
        float cu = Sex;
        float rv[8], cv[8];
        #pragma unroll
        for (int j = 0; j < 8; ++j) {
            cu += u[j];
            Q = fmaxf(Q - u[j], 0.f) + d[j];
            rv[j] = Q + cu;
            cv[j] = cu;
        }
        *(float4*)(Rs  + lane * 8)     = make_float4(rv[0], rv[1], rv[2], rv[3]);
        *(float4*)(Rs  + lane * 8 + 4) = make_float4(rv[4], rv[5], rv[6], rv[7]);
        *(float4*)(CUs + lane * 8)     = make_float4(cv[0], cv[1], cv[2], cv[3]);
        *(float4*)(CUs + lane * 8 + 4) = make_float4(cv[4], cv[5], cv[6], cv[7]);
    }
    barrier_lds_only();                   // publishes Rs/CUs; v stays in flight

    const float cuA = CUs[MIa * 128 + a_t];
    const float cuB = CUs[MIb * 128 + a_t];

    // Stage A (closed form) + B (pack prefetched V) for iteration it_t.
    auto fill = [&](int it_t, int buf) {
        const bool inB = (it_t >= Ka);
        const int  MI  = inB ? MIb : MIa;
        const int  kk  = inB ? (it_t - Ka) : it_t;
        const float cu_t = inB ? cuB : cuA;
        const int  m0  = MI * 128;
        const int  k0  = kk * 32;
        // ---- A: 8 coeffs per thread ----
        {
            const int i = k0 + a_i0;
            const float4 r0 = *(const float4*)(Rs + i);
            const float4 r1 = *(const float4*)(Rs + i + 4);
            const float rv[8] = {r0.x, r0.y, r0.z, r0.w, r1.x, r1.y, r1.z, r1.w};
            const float prev = (i == 0) ? 0.f : Rs[i - 1];
            float pvp = fminf(fmaxf(prev - cu_t, 0.f), 1.f);
            float c[8];
            if (k0 < m0) {                    // strictly below diagonal
                #pragma unroll
                for (int j = 0; j < 8; ++j) {
                    const float pv = fminf(fmaxf(rv[j] - cu_t, 0.f), 1.f);
                    c[j] = pv - pvp;
                    pvp = pv;
                }
            } else {                          // diagonal chunk: zero for i > t
                const int t = m0 + a_t;
                #pragma unroll
                for (int j = 0; j < 8; ++j) {
                    const float pv = fminf(fmaxf(rv[j] - cu_t, 0.f), 1.f);
                    c[j] = (i + j <= t) ? (pv - pvp) : 0.f;
                    pvp = pv;
                }
            }
            uint4 w;
            w.x = bpack(c[0], c[1]); w.y = bpack(c[2], c[3]);
            w.z = bpack(c[4], c[5]); w.w = bpack(c[6], c[7]);
            *(uint4*)(As[buf] + a_t * 40 + a_i0) = w;
        }
        // ---- B: pack prefetched 4k x 2e of V, register transpose ----
        {
            uint2 q0, q1;
            q0.x = bpack(v[0].x, v[1].x); q0.y = bpack(v[2].x, v[3].x);
            q1.x = bpack(v[0].y, v[1].y); q1.y = bpack(v[2].y, v[3].y);
            *(uint2*)(Bs[buf] + b_e2 * 40 + b_k4)       = q0;
            *(uint2*)(Bs[buf] + (b_e2 + 1) * 40 + b_k4) = q1;
        }
    };

    // Issue global V loads for iteration it_t (consumed by fill(it_t)).
    auto prefetch = [&](int it_t) {
        const int kk = (it_t >= Ka) ? (it_t - Ka) : it_t;
        const float* vp = Vb + (size_t)(kk * 32 + b_k4) * (BB * EE);
        #pragma unroll
        for (int r = 0; r < 4; ++r)
            v[r] = *(const float2*)(vp + (size_t)r * (BB * EE));
    };

    f32x4 acc[4][2];
    #pragma unroll
    for (int mi = 0; mi < 4; ++mi)
        #pragma unroll
        for (int ni = 0; ni < 2; ++ni)
            acc[mi][ni] = f32x4{0.f, 0.f, 0.f, 0.f};

    // Epilogue: C/D layout col=lane&15, row=quad*4+r (m89/m91 verified).
    auto epilogue = [&](int m0t) {
        #pragma unroll
        for (int mi = 0; mi < 4; ++mi) {
            #pragma unroll
            for (int r = 0; r < 4; ++r) {
                const int t = m0t + wm + mi * 16 + quad * 4 + r;
                float* orow = out + ((size_t)t * BB + b) * EE + n0 + wn + frow;
                #pragma unroll
                for (int ni = 0; ni < 2; ++ni)
                    orow[ni * 16] = acc[mi][ni][r];
            }
        }
    };

    // Prologue: stage iteration 0 into buf 0, prefetch iteration 1.
    fill(0, 0);
    prefetch(1);
    barrier_lds_only();

    for (int it = 0; it < NIT; ++it) {
        const int cur = it & 1;

        bf16x8 af[4], bf[2];
        #pragma unroll
        for (int mi = 0; mi < 4; ++mi)
            af[mi] = *(const bf16x8*)(As[cur] + (wm + mi * 16 + frow) * 40 + quad * 8);
        #pragma unroll
        for (int ni = 0; ni < 2; ++ni)
            bf[ni] = *(const bf16x8*)(Bs[cur] + (wn + ni * 16 + frow) * 40 + quad * 8);

        if (it + 1 < NIT) {
            fill(it + 1, cur ^ 1);        // writes go to the OTHER buffer
            if (it + 2 < NIT) prefetch(it + 2);
        }

        barrier_lds_only();               // drains LDS only; vmcnt in flight

        #pragma unroll
        for (int mi = 0; mi < 4; ++mi)
            #pragma unroll
            for (int ni = 0; ni < 2; ++ni)
                acc[mi][ni] = __builtin_amdgcn_mfma_f32_16x16x32_bf16(
                    af[mi], bf[ni], acc[mi][ni], 0, 0, 0);

        if (it == Ka - 1) {               // small tile complete: flush + reset
            epilogue(MIa * 128);
            #pragma unroll
            for (int mi = 0; mi < 4; ++mi)
                #pragma unroll
                for (int ni = 0; ni < 2; ++ni)
                    acc[mi][ni] = f32x4{0.f, 0.f, 0.f, 0.f};
        }
    }
    epilogue(MIb * 128);
}

extern "C" void kernel_launch(void* const* d_in, const int* in_sizes, int n_in,
                              void* d_out, int out_size, void* d_ws, size_t ws_size,
                              hipStream_t stream) {
    const float* V = (const float*)d_in[0];   // [T,B,E]
    const float* U = (const float*)d_in[1];   // [T,B]
    const float* D = (const float*)d_in[2];   // [T,B]
    float* out = (float*)d_out;               // [T,B,E]

    gemm_fused_kernel<<<dim3(512), dim3(512), 0, stream>>>(V, U, D, out);
}